// Round 4
// baseline (944.767 us; speedup 1.0000x reference)
//
#include <hip/hip_runtime.h>

#define NB 1024
#define NS 1024
#define NT 32
#define L2E 1.44269504088896340736f
#define LN2 0.69314718055994530942f

typedef short        bfrag  __attribute__((ext_vector_type(8)));   // 8 bf16 (4 VGPR)
typedef float        cfrag  __attribute__((ext_vector_type(16)));  // 16 f32 acc
typedef __bf16       bf16x2 __attribute__((ext_vector_type(2)));
typedef float        f32x8  __attribute__((ext_vector_type(8)));
typedef float        f32x4  __attribute__((ext_vector_type(4)));
typedef float        f32x2  __attribute__((ext_vector_type(2)));
typedef unsigned int u32;
typedef unsigned int u32x4  __attribute__((ext_vector_type(4)));

__device__ __forceinline__ float fexp2(float x){ return __builtin_amdgcn_exp2f(x); }
__device__ __forceinline__ float flog2(float x){ return __builtin_amdgcn_logf(x); }

// RNE pack (prologue only)
__device__ __forceinline__ u32 pkbf_rne(float a, float b){
    f32x2 t; t.x = a; t.y = b;
    return __builtin_bit_cast(u32, __builtin_convertvector(t, bf16x2));
}
// truncation pack: single v_perm_b32. low16 = bf16_trunc(a), high16 = bf16_trunc(b).
__device__ __forceinline__ u32 pkbf_t(float a, float b){
    return __builtin_amdgcn_perm(__builtin_bit_cast(u32, b),
                                 __builtin_bit_cast(u32, a), 0x07060302u);
}
__device__ __forceinline__ bfrag mk_afrag(f32x8 v){
    u32x4 r;
    r[0] = pkbf_rne(v[0], v[1]); r[1] = pkbf_rne(v[2], v[3]);
    r[2] = pkbf_rne(v[4], v[5]); r[3] = pkbf_rne(v[6], v[7]);
    return __builtin_bit_cast(bfrag, r);
}
// unpack stored bf16 (lo==0 -> low16, lo==1 -> high16) to f32
__device__ __forceinline__ float ubf(u32 x, int lo){
    return __builtin_bit_cast(float, lo ? (x & 0xFFFF0000u) : (x << 16));
}

// row-space involution applied implicitly by packing C/D straight into B regs:
// swaps row blocks [4..7]<->[8..11] and [20..23]<->[24..27].
__device__ __forceinline__ int rho(int k){
    int bb = (k >> 2) & 3;
    return (bb == 1 || bb == 2) ? (k ^ 12) : k;
}

template<int N> struct ic { static constexpr int value = N; };
union accu { cfrag c; f32x2 p[8]; };
union q4u  { f32x4 v; f32x2 p[2]; };

// ---------------- Single fused kernel ----------------
// Per-(batch,chunk) wave: 32x32 transfer matrix in rho space (round-3 verified),
// then post-loop gold for its own 128 positions, then last-arriver-per-batch
// election: the 8th wave of a batch runs the in-wave 8-round matvec (linear
// space, power-of-2 renorm, shuffle broadcasts, no LDS/sync) and accumulates
// logZ - gold into a workspace accumulator; the 1024th election writes *out.
__global__ __launch_bounds__(256, 8) void crf_fused(
    const float* __restrict__ logits, const float* __restrict__ trans,
    const int* __restrict__ tags, const int* __restrict__ lens,
    u32* __restrict__ wmat, float* __restrict__ woff,
    float* __restrict__ gacc, int* __restrict__ cnt,
    float* __restrict__ outac, int* __restrict__ nfin,
    float* __restrict__ out)
{
    __shared__ __align__(16) float dscall[4 * 512];   // per-wave: 2 bufs x 8 steps x 32

    const int tid = threadIdx.x;
    const int wv  = tid >> 6, lt = tid & 63;
    const int m   = lt & 31,  h  = lt >> 5;
    const int bc  = blockIdx.x * 4 + wv;
    const int b   = bc >> 3,  c  = bc & 7;
    float* dsc = dscall + wv * 512;

    const float* base = logits + (size_t)b * NS * NT;
    const int    len  = lens[b];
    const int    tb   = b * NS;

    // A frags with rho-compensated k index: A'[m][k] = exp(trans[rho(k)][m])
    f32x8 Et0, Et1;
    #pragma unroll
    for (int j = 0; j < 8; j++){
        Et0[j] = fexp2(L2E * trans[rho(     8*h + j)*NT + m]);
        Et1[j] = fexp2(L2E * trans[rho(16 + 8*h + j)*NT + m]);
    }
    const bfrag A0f = mk_afrag(Et0);
    const bfrag A1f = mk_afrag(Et1);

    // B = rho-permuted identity (packed bf16): slot k holds row rho(k)
    u32x4 B0v, B1v;
    #pragma unroll
    for (int d = 0; d < 4; d++){
        int k0 = 8*h + 2*d;      u32 v = 0;
        if (rho(k0)     == m) v |= 0x3F80u;
        if (rho(k0 + 1) == m) v |= 0x3F800000u;
        B0v[d] = v;
        int k1 = 16 + 8*h + 2*d; v = 0;
        if (rho(k1)     == m) v |= 0x3F80u;
        if (rho(k1 + 1) == m) v |= 0x3F800000u;
        B1v[d] = v;
    }

    cfrag zacc;
    #pragma unroll
    for (int q = 0; q < 16; q++) zacc[q] = 0.0f;

    int   offi = 0;        // accumulated log2 scale (integer, wave-uniform)
    float exf  = 0.0f;     // deferred scale folded into next block's step-0 D
    const int tbeg = c*128 + 1;

    float eA[4], eB[4];

    auto issue = [&](float (&e)[4], int k){
        const int t0 = tbeg + k*8 + 4*h;
        #pragma unroll
        for (int i = 0; i < 4; i++){
            int t = t0 + i; t = t > (NS-1) ? (NS-1) : t;   // clamp c==7 tail
            e[i] = base[t*NT + m];
        }
    };
    auto commit = [&](float (&e)[4], int k){
        float* sp = dsc + (k & 1)*256 + (4*h)*32 + m;
        float a0 = (h == 0) ? -exf : 0.0f;
        sp[0]    = fexp2(fmaf(L2E, e[0], a0));
        sp[32]   = fexp2(L2E * e[1]);
        sp[64]   = fexp2(L2E * e[2]);
        sp[96]   = fexp2(L2E * e[3]);
    };

    auto exref = [&](float ref)->int{
        u32 xb = __builtin_bit_cast(u32, ref);
        u32 xf = __builtin_amdgcn_readfirstlane(xb);
        int ex = (int)((xf >> 23) & 0xFFu) - 127;
        return ex < -120 ? -120 : (ex > 120 ? 120 : ex);
    };

    auto procN = [&](int k, bool defer, auto nstc){
        constexpr int NST = decltype(nstc)::value;
        const float* db = dsc + (k & 1)*256 + 4*h;
        #pragma unroll
        for (int i = 0; i < NST; i++){
            accu acc;
            acc.c = __builtin_amdgcn_mfma_f32_32x32x16_bf16(
                        A0f, __builtin_bit_cast(bfrag, B0v), zacc, 0, 0, 0);
            acc.c = __builtin_amdgcn_mfma_f32_32x32x16_bf16(
                        A1f, __builtin_bit_cast(bfrag, B1v), acc.c, 0, 0, 0);

            // D_t row scales (true row space; unaffected by rho)
            q4u d0, d1, d2, d3;
            d0.v = *(const f32x4*)(db + i*32 +  0);
            d1.v = *(const f32x4*)(db + i*32 +  8);
            d2.v = *(const f32x4*)(db + i*32 + 16);
            d3.v = *(const f32x4*)(db + i*32 + 24);
            acc.p[0] *= d0.p[0]; acc.p[1] *= d0.p[1];
            acc.p[2] *= d1.p[0]; acc.p[3] *= d1.p[1];
            acc.p[4] *= d2.p[0]; acc.p[5] *= d2.p[1];
            acc.p[6] *= d3.p[0]; acc.p[7] *= d3.p[1];

            if (i == 3){
                int ex = exref(fmaxf(acc.c[0], acc.c[8]));
                offi += ex;
                f32x2 s2;
                s2.x = s2.y = __builtin_bit_cast(float, (u32)(127 - ex) << 23);
                #pragma unroll
                for (int q = 0; q < 8; q++) acc.p[q] *= s2;
            }
            if (i == 7 && defer){
                int ex = exref(fmaxf(acc.c[0], acc.c[8]));
                offi += ex;
                exf = (float)ex;
            }

            // pack C/D straight into B regs (lane-local; applies rho implicitly)
            B0v[0] = pkbf_t(acc.c[0],  acc.c[1]);  B0v[1] = pkbf_t(acc.c[2],  acc.c[3]);
            B0v[2] = pkbf_t(acc.c[4],  acc.c[5]);  B0v[3] = pkbf_t(acc.c[6],  acc.c[7]);
            B1v[0] = pkbf_t(acc.c[8],  acc.c[9]);  B1v[1] = pkbf_t(acc.c[10], acc.c[11]);
            B1v[2] = pkbf_t(acc.c[12], acc.c[13]); B1v[3] = pkbf_t(acc.c[14], acc.c[15]);
        }
    };

    issue(eA, 0); commit(eA, 0);
    #pragma unroll 1
    for (int k = 0; k < 14; k += 2){
        issue(eB, k + 1);
        procN(k, true, ic<8>{});
        commit(eB, k + 1);
        issue(eA, k + 2);
        procN(k + 1, true, ic<8>{});
        commit(eA, k + 2);
    }
    issue(eB, 15);
    procN(14, true, ic<8>{});
    commit(eB, 15);
    if (c != 7) procN(15, false, ic<8>{});   // wave-uniform branch
    else        procN(15, false, ic<7>{});   // chunk 7 has 127 steps

    // ---- store M~ = rho(M) in B-frag form: wmat[bc*512 + d*64 + lane]
    const size_t mb = (size_t)bc * 512;
    #pragma unroll
    for (int d = 0; d < 4; d++){
        wmat[mb + d*64 + lt]     = B0v[d];
        wmat[mb + (4+d)*64 + lt] = B1v[d];
    }
    if (lt == 0) woff[bc] = (float)offi;

    // ---- gold for this chunk's 128 positions (t = tbeg..tbeg+127), 2/lane.
    // Post-loop: no register-pressure interaction with the hot loop (r2 lesson).
    {
        const int t1 = tbeg + 2*lt;
        const int t2 = t1 + 1;
        const int i2 = t2 > (NS-1) ? (NS-1) : t2;   // c==7,lt==63: t2==1024
        const int g0 = tags[tb + t1 - 1];
        const int g1 = tags[tb + t1];
        const int g2 = tags[tb + i2];
        float gg = 0.0f;
        if (t1 < len) gg += base[t1*NT + g1] + trans[g0*NT + g1];
        if (t2 < len) gg += base[t2*NT + g2] + trans[g1*NT + g2];
        #pragma unroll
        for (int d = 1; d < 64; d <<= 1) gg += __shfl_xor(gg, d, 64);
        if (lt == 0){
            if (c == 0) gg += base[tags[tb]];        // t=0 emission
            atomicAdd(&gacc[b], gg);
        }
    }

    // ---- election: 8th arriver of batch b runs the combine
    __threadfence();                                  // release wmat/woff/gacc
    int old = 0;
    if (lt == 0) old = atomicAdd(&cnt[b], 1);
    old = __shfl(old, 0, 64);
    if (old != 7) return;

    __threadfence();                                  // acquire others' stores

    // in-wave combine: v_{c+1} = 2^offs[c] * M_c v_c, linear space, pow2 renorm.
    // stored row n of M lives at slot nn=rho(n): 32 consecutive dwords at segbase.
    const int n   = lt & 31;
    const int bb2 = (n >> 2) & 3;
    const int nn  = (bb2 == 1 || bb2 == 2) ? (n ^ 12) : n;
    const int segbase = (nn >> 4)*256 + ((nn >> 3) & 1)*32 + ((nn >> 1) & 3)*64;
    const int lo  = nn & 1;
    const u32* wbm = wmat + (size_t)b * 8 * 512 + segbase;

    float offs[8];
    #pragma unroll
    for (int cc = 0; cc < 8; cc++) offs[cc] = woff[b*8 + cc];

    float v    = fexp2(L2E * base[n]);    // t=0 emissions (cols 0..31; dup in hi half)
    float voff = 0.0f;

    #pragma unroll
    for (int cc = 0; cc < 8; cc++){
        uint4 md[8];
        const uint4* mp = (const uint4*)(wbm + cc*512);
        #pragma unroll
        for (int qq = 0; qq < 8; qq++) md[qq] = mp[qq];

        float acc = 0.0f;
        #pragma unroll
        for (int qq = 0; qq < 8; qq++){
            float u0 = __shfl(v, 4*qq + 0, 64);
            float u1 = __shfl(v, 4*qq + 1, 64);
            float u2 = __shfl(v, 4*qq + 2, 64);
            float u3 = __shfl(v, 4*qq + 3, 64);
            acc = fmaf(ubf(md[qq].x, lo), u0, acc);
            acc = fmaf(ubf(md[qq].y, lo), u1, acc);
            acc = fmaf(ubf(md[qq].z, lo), u2, acc);
            acc = fmaf(ubf(md[qq].w, lo), u3, acc);
        }
        float mx = acc;
        #pragma unroll
        for (int d = 1; d <= 16; d <<= 1) mx = fmaxf(mx, __shfl_xor(mx, d, 64));
        int ex = exref(mx);
        v = acc * __builtin_bit_cast(float, (u32)(127 - ex) << 23);
        voff += (float)ex + offs[cc];
    }

    float s = v;
    #pragma unroll
    for (int d = 1; d <= 16; d <<= 1) s += __shfl_xor(s, d, 64);   // sum over 32 tags

    if (lt == 0){
        float gold = atomicAdd(&gacc[b], 0.0f);       // coherent read
        float logz = LN2 * (voff + flog2(s));
        atomicAdd(outac, (logz - gold) * (1.0f / (float)NB));
        __threadfence();
        int t2e = atomicAdd(nfin, 1);
        if (t2e == NB - 1){                            // last batch done -> publish
            __threadfence();
            *out = atomicAdd(outac, 0.0f);
        }
    }
}

extern "C" void kernel_launch(void* const* d_in, const int* in_sizes, int n_in,
                              void* d_out, int out_size, void* d_ws, size_t ws_size,
                              hipStream_t stream) {
    const float* logits = (const float*)d_in[0];
    const float* trans  = (const float*)d_in[1];
    const int*   tags   = (const int*)d_in[2];
    const int*   lens   = (const int*)d_in[3];

    u32*   wmat  = (u32*)d_ws;                                   // 16 MB
    float* woff  = (float*)((char*)d_ws + 16u*1024u*1024u);      // 32 KB
    char*  ctl   = (char*)d_ws + 16u*1024u*1024u + 32u*1024u;    // control block
    float* gacc  = (float*)ctl;                                  // 1024 f32
    int*   cnt   = (int*)(ctl + 4096);                           // 1024 i32
    float* outac = (float*)(ctl + 8192);                         // 1 f32
    int*   nfin  = (int*)(ctl + 8192 + 4);                       // 1 i32

    hipMemsetAsync(ctl, 0, 8448, stream);
    crf_fused<<<2048, 256, 0, stream>>>(logits, trans, tags, lens,
                                        wmat, woff, gacc, cnt, outac, nfin,
                                        (float*)d_out);
}

// Round 5
// 252.397 us; speedup vs baseline: 3.7432x; 3.7432x over previous
//
#include <hip/hip_runtime.h>

#define NB 1024
#define NS 1024
#define NT 32
#define L2E 1.44269504088896340736f
#define LN2 0.69314718055994530942f

typedef short        bfrag  __attribute__((ext_vector_type(8)));   // 8 bf16 (4 VGPR)
typedef float        cfrag  __attribute__((ext_vector_type(16)));  // 16 f32 acc
typedef __bf16       bf16x2 __attribute__((ext_vector_type(2)));
typedef float        f32x8  __attribute__((ext_vector_type(8)));
typedef float        f32x4  __attribute__((ext_vector_type(4)));
typedef float        f32x2  __attribute__((ext_vector_type(2)));
typedef unsigned int u32;
typedef unsigned int u32x4  __attribute__((ext_vector_type(4)));

__device__ __forceinline__ float fexp2(float x){ return __builtin_amdgcn_exp2f(x); }
__device__ __forceinline__ float flog2(float x){ return __builtin_amdgcn_logf(x); }

// RNE pack (prologue only)
__device__ __forceinline__ u32 pkbf_rne(float a, float b){
    f32x2 t; t.x = a; t.y = b;
    return __builtin_bit_cast(u32, __builtin_convertvector(t, bf16x2));
}
// truncation pack: single v_perm_b32. low16 = bf16_trunc(a), high16 = bf16_trunc(b).
__device__ __forceinline__ u32 pkbf_t(float a, float b){
    return __builtin_amdgcn_perm(__builtin_bit_cast(u32, b),
                                 __builtin_bit_cast(u32, a), 0x07060302u);
}
__device__ __forceinline__ bfrag mk_afrag(f32x8 v){
    u32x4 r;
    r[0] = pkbf_rne(v[0], v[1]); r[1] = pkbf_rne(v[2], v[3]);
    r[2] = pkbf_rne(v[4], v[5]); r[3] = pkbf_rne(v[6], v[7]);
    return __builtin_bit_cast(bfrag, r);
}
// unpack stored bf16 (lo==0 -> low16, lo==1 -> high16) to f32
__device__ __forceinline__ float ubf(u32 x, int lo){
    return __builtin_bit_cast(float, lo ? (x & 0xFFFF0000u) : (x << 16));
}
// wave-uniform power-of-2 exponent extract (clamped)
__device__ __forceinline__ int exref(float ref){
    u32 xb = __builtin_bit_cast(u32, ref);
    u32 xf = __builtin_amdgcn_readfirstlane(xb);
    int ex = (int)((xf >> 23) & 0xFFu) - 127;
    return ex < -120 ? -120 : (ex > 120 ? 120 : ex);
}

// row-space involution applied implicitly by packing C/D straight into B regs:
// swaps row blocks [4..7]<->[8..11] and [20..23]<->[24..27].
__device__ __forceinline__ int rho(int k){
    int bb = (k >> 2) & 3;
    return (bb == 1 || bb == 2) ? (k ^ 12) : k;
}

template<int N> struct ic { static constexpr int value = N; };
union accu { cfrag c; f32x2 p[8]; };
union q4u  { f32x4 v; f32x2 p[2]; };

// ---------------- Phase 1: per-(batch,chunk) 32x32 transfer matrix + gold -------
// Hot loop identical to round 3 (97 µs verified). Gold for this wave's own 128
// positions is computed POST-loop (r4-verified code): emissions are L1/L2-hot
// (this wave just streamed them), tags loads are coalesced across lanes.
// Partial -> plain store gpart[bc]; no atomics, no fences (r4 lesson: device
// fences inside a dispatch flush non-coherent L2s and serialize the chip).
__global__ __launch_bounds__(256, 8) void crf_chunk(
    const float* __restrict__ logits, const float* __restrict__ trans,
    const int* __restrict__ tags, const int* __restrict__ lens,
    u32* __restrict__ wmat, float* __restrict__ woff,
    float* __restrict__ gpart, float* __restrict__ outz)
{
    __shared__ __align__(16) float dscall[4 * 512];   // per-wave: 2 bufs x 8 steps x 32

    const int tid = threadIdx.x;
    const int wv  = tid >> 6, lt = tid & 63;
    const int m   = lt & 31,  h  = lt >> 5;
    const int bc  = blockIdx.x * 4 + wv;
    const int b   = bc >> 3,  c  = bc & 7;
    float* dsc = dscall + wv * 512;

    if (blockIdx.x == 0 && tid == 0) *outz = 0.0f;    // replaces memset dispatch

    const float* base = logits + (size_t)b * NS * NT;
    const int    len  = lens[b];
    const int    tb   = b * NS;

    // A frags with rho-compensated k index: A'[m][k] = exp(trans[rho(k)][m])
    f32x8 Et0, Et1;
    #pragma unroll
    for (int j = 0; j < 8; j++){
        Et0[j] = fexp2(L2E * trans[rho(     8*h + j)*NT + m]);
        Et1[j] = fexp2(L2E * trans[rho(16 + 8*h + j)*NT + m]);
    }
    const bfrag A0f = mk_afrag(Et0);
    const bfrag A1f = mk_afrag(Et1);

    // B = rho-permuted identity (packed bf16): slot k holds row rho(k)
    u32x4 B0v, B1v;
    #pragma unroll
    for (int d = 0; d < 4; d++){
        int k0 = 8*h + 2*d;      u32 v = 0;
        if (rho(k0)     == m) v |= 0x3F80u;
        if (rho(k0 + 1) == m) v |= 0x3F800000u;
        B0v[d] = v;
        int k1 = 16 + 8*h + 2*d; v = 0;
        if (rho(k1)     == m) v |= 0x3F80u;
        if (rho(k1 + 1) == m) v |= 0x3F800000u;
        B1v[d] = v;
    }

    cfrag zacc;
    #pragma unroll
    for (int q = 0; q < 16; q++) zacc[q] = 0.0f;

    int   offi = 0;        // accumulated log2 scale (integer, wave-uniform)
    float exf  = 0.0f;     // deferred scale folded into next block's step-0 D
    const int tbeg = c*128 + 1;

    float eA[4], eB[4];

    auto issue = [&](float (&e)[4], int k){
        const int t0 = tbeg + k*8 + 4*h;
        #pragma unroll
        for (int i = 0; i < 4; i++){
            int t = t0 + i; t = t > (NS-1) ? (NS-1) : t;   // clamp c==7 tail
            e[i] = base[t*NT + m];
        }
    };
    auto commit = [&](float (&e)[4], int k){
        float* sp = dsc + (k & 1)*256 + (4*h)*32 + m;
        float a0 = (h == 0) ? -exf : 0.0f;
        sp[0]    = fexp2(fmaf(L2E, e[0], a0));
        sp[32]   = fexp2(L2E * e[1]);
        sp[64]   = fexp2(L2E * e[2]);
        sp[96]   = fexp2(L2E * e[3]);
    };

    auto procN = [&](int k, bool defer, auto nstc){
        constexpr int NST = decltype(nstc)::value;
        const float* db = dsc + (k & 1)*256 + 4*h;
        #pragma unroll
        for (int i = 0; i < NST; i++){
            accu acc;
            acc.c = __builtin_amdgcn_mfma_f32_32x32x16_bf16(
                        A0f, __builtin_bit_cast(bfrag, B0v), zacc, 0, 0, 0);
            acc.c = __builtin_amdgcn_mfma_f32_32x32x16_bf16(
                        A1f, __builtin_bit_cast(bfrag, B1v), acc.c, 0, 0, 0);

            // D_t row scales (true row space; unaffected by rho)
            q4u d0, d1, d2, d3;
            d0.v = *(const f32x4*)(db + i*32 +  0);
            d1.v = *(const f32x4*)(db + i*32 +  8);
            d2.v = *(const f32x4*)(db + i*32 + 16);
            d3.v = *(const f32x4*)(db + i*32 + 24);
            acc.p[0] *= d0.p[0]; acc.p[1] *= d0.p[1];
            acc.p[2] *= d1.p[0]; acc.p[3] *= d1.p[1];
            acc.p[4] *= d2.p[0]; acc.p[5] *= d2.p[1];
            acc.p[6] *= d3.p[0]; acc.p[7] *= d3.p[1];

            if (i == 3){
                int ex = exref(fmaxf(acc.c[0], acc.c[8]));
                offi += ex;
                f32x2 s2;
                s2.x = s2.y = __builtin_bit_cast(float, (u32)(127 - ex) << 23);
                #pragma unroll
                for (int q = 0; q < 8; q++) acc.p[q] *= s2;
            }
            if (i == 7 && defer){
                int ex = exref(fmaxf(acc.c[0], acc.c[8]));
                offi += ex;
                exf = (float)ex;
            }

            // pack C/D straight into B regs (lane-local; applies rho implicitly)
            B0v[0] = pkbf_t(acc.c[0],  acc.c[1]);  B0v[1] = pkbf_t(acc.c[2],  acc.c[3]);
            B0v[2] = pkbf_t(acc.c[4],  acc.c[5]);  B0v[3] = pkbf_t(acc.c[6],  acc.c[7]);
            B1v[0] = pkbf_t(acc.c[8],  acc.c[9]);  B1v[1] = pkbf_t(acc.c[10], acc.c[11]);
            B1v[2] = pkbf_t(acc.c[12], acc.c[13]); B1v[3] = pkbf_t(acc.c[14], acc.c[15]);
        }
    };

    issue(eA, 0); commit(eA, 0);
    #pragma unroll 1
    for (int k = 0; k < 14; k += 2){
        issue(eB, k + 1);
        procN(k, true, ic<8>{});
        commit(eB, k + 1);
        issue(eA, k + 2);
        procN(k + 1, true, ic<8>{});
        commit(eA, k + 2);
    }
    issue(eB, 15);
    procN(14, true, ic<8>{});
    commit(eB, 15);
    if (c != 7) procN(15, false, ic<8>{});   // wave-uniform branch
    else        procN(15, false, ic<7>{});   // chunk 7 has 127 steps

    // ---- store M~ = rho(M) in B-frag form: wmat[bc*512 + d*64 + lane]
    const size_t mb = (size_t)bc * 512;
    #pragma unroll
    for (int d = 0; d < 4; d++){
        wmat[mb + d*64 + lt]     = B0v[d];
        wmat[mb + (4+d)*64 + lt] = B1v[d];
    }
    if (lt == 0) woff[bc] = (float)offi;

    // ---- gold for this chunk's 128 positions (t = tbeg..tbeg+127), 2/lane.
    // Post-loop (r4-verified): emissions just streamed by this wave -> cache-hot.
    {
        const int t1 = tbeg + 2*lt;
        const int t2 = t1 + 1;
        const int i2 = t2 > (NS-1) ? (NS-1) : t2;   // c==7,lt==63: t2==1024
        const int g0 = tags[tb + t1 - 1];
        const int g1 = tags[tb + t1];
        const int g2 = tags[tb + i2];
        float gg = 0.0f;
        if (t1 < len) gg += base[t1*NT + g1] + trans[g0*NT + g1];
        if (t2 < len) gg += base[t2*NT + g2] + trans[g1*NT + g2];
        #pragma unroll
        for (int d = 1; d < 64; d <<= 1) gg += __shfl_xor(gg, d, 64);
        if (lt == 0){
            if (c == 0) gg += base[tags[tb]];        // t=0 emission
            gpart[bc] = gg;                          // plain store, no atomic
        }
    }
}

// ---------------- Phase 2: per-batch in-wave combine ----------------
// 1024 blocks x 1 wave. No LDS, no __syncthreads: shuffle-broadcast matvec in
// linear space with power-of-2 renorm (r4-verified math). Register double-buffer
// prefetch hides the next chunk-matrix load under the current round's compute.
__global__ __launch_bounds__(64) void crf_combine(
    const float* __restrict__ logits, const int* __restrict__ tags,
    const u32* __restrict__ wmat, const float* __restrict__ woff,
    const float* __restrict__ gpart, float* __restrict__ out)
{
    const int lt = threadIdx.x;
    const int b  = blockIdx.x;
    const float* base = logits + (size_t)b * NS * NT;

    // gold: fold 8 chunk partials + t=0 emission (uniform scalar loads)
    float4 gp0 = ((const float4*)(gpart + b*8))[0];
    float4 gp1 = ((const float4*)(gpart + b*8))[1];
    const float gold = (gp0.x + gp0.y) + (gp0.z + gp0.w)
                     + (gp1.x + gp1.y) + (gp1.z + gp1.w);

    float offs[8];
    #pragma unroll
    for (int cc = 0; cc < 8; cc++) offs[cc] = woff[b*8 + cc];

    // stored row n of M lives at slot nn=rho(n): 32 consecutive dwords at segbase
    const int n   = lt & 31;
    const int bb2 = (n >> 2) & 3;
    const int nn  = (bb2 == 1 || bb2 == 2) ? (n ^ 12) : n;
    const int segbase = (nn >> 4)*256 + ((nn >> 3) & 1)*32 + ((nn >> 1) & 3)*64;
    const int lo  = nn & 1;
    const u32* wbm = wmat + (size_t)b * 8 * 512 + segbase;

    float v    = fexp2(L2E * base[n]);    // t=0 emissions (hi half duplicates)
    float voff = 0.0f;

    uint4 mdA[8], mdB[8];
    {
        const uint4* mp = (const uint4*)(wbm);
        #pragma unroll
        for (int qq = 0; qq < 8; qq++) mdA[qq] = mp[qq];
    }

    #pragma unroll
    for (int cc = 0; cc < 8; cc++){
        uint4 (&cur)[8] = (cc & 1) ? mdB : mdA;
        uint4 (&nxt)[8] = (cc & 1) ? mdA : mdB;
        if (cc < 7){
            const uint4* mp = (const uint4*)(wbm + (cc + 1)*512);
            #pragma unroll
            for (int qq = 0; qq < 8; qq++) nxt[qq] = mp[qq];
        }

        float acc = 0.0f;
        #pragma unroll
        for (int qq = 0; qq < 8; qq++){
            float u0 = __shfl(v, 4*qq + 0, 64);
            float u1 = __shfl(v, 4*qq + 1, 64);
            float u2 = __shfl(v, 4*qq + 2, 64);
            float u3 = __shfl(v, 4*qq + 3, 64);
            acc = fmaf(ubf(cur[qq].x, lo), u0, acc);
            acc = fmaf(ubf(cur[qq].y, lo), u1, acc);
            acc = fmaf(ubf(cur[qq].z, lo), u2, acc);
            acc = fmaf(ubf(cur[qq].w, lo), u3, acc);
        }
        float mx = acc;
        #pragma unroll
        for (int d = 1; d <= 16; d <<= 1) mx = fmaxf(mx, __shfl_xor(mx, d, 64));
        int ex = exref(mx);
        v = acc * __builtin_bit_cast(float, (u32)(127 - ex) << 23);
        voff += (float)ex + offs[cc];
    }

    float s = v;
    #pragma unroll
    for (int d = 1; d <= 16; d <<= 1) s += __shfl_xor(s, d, 64);   // sum over 32 tags

    if (lt == 0){
        float logz = LN2 * (voff + flog2(s));
        atomicAdd(out, (logz - gold) * (1.0f / (float)NB));
    }
}

extern "C" void kernel_launch(void* const* d_in, const int* in_sizes, int n_in,
                              void* d_out, int out_size, void* d_ws, size_t ws_size,
                              hipStream_t stream) {
    const float* logits = (const float*)d_in[0];
    const float* trans  = (const float*)d_in[1];
    const int*   tags   = (const int*)d_in[2];
    const int*   lens   = (const int*)d_in[3];

    u32*   wmat  = (u32*)d_ws;                                   // 16 MB
    float* woff  = (float*)((char*)d_ws + 16u*1024u*1024u);      // 32 KB
    float* gpart = woff + 8192;                                  // 32 KB

    crf_chunk  <<<2048, 256, 0, stream>>>(logits, trans, tags, lens,
                                          wmat, woff, gpart, (float*)d_out);
    crf_combine<<<1024,  64, 0, stream>>>(logits, tags, wmat, woff, gpart,
                                          (float*)d_out);
}

// Round 6
// 248.456 us; speedup vs baseline: 3.8025x; 1.0159x over previous
//
#include <hip/hip_runtime.h>

#define NB 1024
#define NS 1024
#define NT 32
#define L2E 1.44269504088896340736f
#define LN2 0.69314718055994530942f

typedef short        bfrag  __attribute__((ext_vector_type(8)));   // 8 bf16 (4 VGPR)
typedef float        cfrag  __attribute__((ext_vector_type(16)));  // 16 f32 acc
typedef __bf16       bf16x2 __attribute__((ext_vector_type(2)));
typedef float        f32x8  __attribute__((ext_vector_type(8)));
typedef float        f32x4  __attribute__((ext_vector_type(4)));
typedef float        f32x2  __attribute__((ext_vector_type(2)));
typedef unsigned int u32;
typedef unsigned int u32x4  __attribute__((ext_vector_type(4)));

__device__ __forceinline__ float fexp2(float x){ return __builtin_amdgcn_exp2f(x); }
__device__ __forceinline__ float flog2(float x){ return __builtin_amdgcn_logf(x); }

// RNE pack (prologue only)
__device__ __forceinline__ u32 pkbf_rne(float a, float b){
    f32x2 t; t.x = a; t.y = b;
    return __builtin_bit_cast(u32, __builtin_convertvector(t, bf16x2));
}
// truncation pack: single v_perm_b32. low16 = bf16_trunc(a), high16 = bf16_trunc(b).
__device__ __forceinline__ u32 pkbf_t(float a, float b){
    return __builtin_amdgcn_perm(__builtin_bit_cast(u32, b),
                                 __builtin_bit_cast(u32, a), 0x07060302u);
}
__device__ __forceinline__ bfrag mk_afrag(f32x8 v){
    u32x4 r;
    r[0] = pkbf_rne(v[0], v[1]); r[1] = pkbf_rne(v[2], v[3]);
    r[2] = pkbf_rne(v[4], v[5]); r[3] = pkbf_rne(v[6], v[7]);
    return __builtin_bit_cast(bfrag, r);
}
// wave-uniform power-of-2 exponent extract (clamped)
__device__ __forceinline__ int exref(float ref){
    u32 xb = __builtin_bit_cast(u32, ref);
    u32 xf = __builtin_amdgcn_readfirstlane(xb);
    int ex = (int)((xf >> 23) & 0xFFu) - 127;
    return ex < -120 ? -120 : (ex > 120 ? 120 : ex);
}

// row-space involution applied implicitly by packing C/D straight into B regs:
// swaps row blocks [4..7]<->[8..11] and [20..23]<->[24..27].
__device__ __forceinline__ int rho(int k){
    int bb = (k >> 2) & 3;
    return (bb == 1 || bb == 2) ? (k ^ 12) : k;
}

template<int N> struct ic { static constexpr int value = N; };
union accu { cfrag c; f32x2 p[8]; };
union q4u  { f32x4 v; f32x2 p[2]; };

// ---------------- Phase 1: per-(batch,chunk) 32x32 transfer matrix + gold -------
// Hot loop identical to round 3/5 (95.5 µs verified). Store layout changed:
// each lane's 8 frag dwords are now CONTIGUOUS (wmat[bc*512 + lt*8 + d]) so the
// combine kernel can reload the exact fragment with 2 dwordx4 per matrix
// (2 KB/matrix, no replication — r5 combine re-read each matrix 4x).
__global__ __launch_bounds__(256, 8) void crf_chunk(
    const float* __restrict__ logits, const float* __restrict__ trans,
    const int* __restrict__ tags, const int* __restrict__ lens,
    u32* __restrict__ wmat, float* __restrict__ woff,
    float* __restrict__ gpart, float* __restrict__ outz)
{
    __shared__ __align__(16) float dscall[4 * 512];   // per-wave: 2 bufs x 8 steps x 32

    const int tid = threadIdx.x;
    const int wv  = tid >> 6, lt = tid & 63;
    const int m   = lt & 31,  h  = lt >> 5;
    const int bc  = blockIdx.x * 4 + wv;
    const int b   = bc >> 3,  c  = bc & 7;
    float* dsc = dscall + wv * 512;

    if (blockIdx.x == 0 && tid == 0) *outz = 0.0f;    // replaces memset dispatch

    const float* base = logits + (size_t)b * NS * NT;
    const int    len  = lens[b];
    const int    tb   = b * NS;

    // A frags with rho-compensated k index: A'[m][k] = exp(trans[rho(k)][m])
    f32x8 Et0, Et1;
    #pragma unroll
    for (int j = 0; j < 8; j++){
        Et0[j] = fexp2(L2E * trans[rho(     8*h + j)*NT + m]);
        Et1[j] = fexp2(L2E * trans[rho(16 + 8*h + j)*NT + m]);
    }
    const bfrag A0f = mk_afrag(Et0);
    const bfrag A1f = mk_afrag(Et1);

    // B = rho-permuted identity (packed bf16): slot k holds row rho(k)
    u32x4 B0v, B1v;
    #pragma unroll
    for (int d = 0; d < 4; d++){
        int k0 = 8*h + 2*d;      u32 v = 0;
        if (rho(k0)     == m) v |= 0x3F80u;
        if (rho(k0 + 1) == m) v |= 0x3F800000u;
        B0v[d] = v;
        int k1 = 16 + 8*h + 2*d; v = 0;
        if (rho(k1)     == m) v |= 0x3F80u;
        if (rho(k1 + 1) == m) v |= 0x3F800000u;
        B1v[d] = v;
    }

    cfrag zacc;
    #pragma unroll
    for (int q = 0; q < 16; q++) zacc[q] = 0.0f;

    int   offi = 0;        // accumulated log2 scale (integer, wave-uniform)
    float exf  = 0.0f;     // deferred scale folded into next block's step-0 D
    const int tbeg = c*128 + 1;

    float eA[4], eB[4];

    auto issue = [&](float (&e)[4], int k){
        const int t0 = tbeg + k*8 + 4*h;
        #pragma unroll
        for (int i = 0; i < 4; i++){
            int t = t0 + i; t = t > (NS-1) ? (NS-1) : t;   // clamp c==7 tail
            e[i] = base[t*NT + m];
        }
    };
    auto commit = [&](float (&e)[4], int k){
        float* sp = dsc + (k & 1)*256 + (4*h)*32 + m;
        float a0 = (h == 0) ? -exf : 0.0f;
        sp[0]    = fexp2(fmaf(L2E, e[0], a0));
        sp[32]   = fexp2(L2E * e[1]);
        sp[64]   = fexp2(L2E * e[2]);
        sp[96]   = fexp2(L2E * e[3]);
    };

    auto procN = [&](int k, bool defer, auto nstc){
        constexpr int NST = decltype(nstc)::value;
        const float* db = dsc + (k & 1)*256 + 4*h;
        #pragma unroll
        for (int i = 0; i < NST; i++){
            accu acc;
            acc.c = __builtin_amdgcn_mfma_f32_32x32x16_bf16(
                        A0f, __builtin_bit_cast(bfrag, B0v), zacc, 0, 0, 0);
            acc.c = __builtin_amdgcn_mfma_f32_32x32x16_bf16(
                        A1f, __builtin_bit_cast(bfrag, B1v), acc.c, 0, 0, 0);

            // D_t row scales (true row space; unaffected by rho)
            q4u d0, d1, d2, d3;
            d0.v = *(const f32x4*)(db + i*32 +  0);
            d1.v = *(const f32x4*)(db + i*32 +  8);
            d2.v = *(const f32x4*)(db + i*32 + 16);
            d3.v = *(const f32x4*)(db + i*32 + 24);
            acc.p[0] *= d0.p[0]; acc.p[1] *= d0.p[1];
            acc.p[2] *= d1.p[0]; acc.p[3] *= d1.p[1];
            acc.p[4] *= d2.p[0]; acc.p[5] *= d2.p[1];
            acc.p[6] *= d3.p[0]; acc.p[7] *= d3.p[1];

            if (i == 3){
                int ex = exref(fmaxf(acc.c[0], acc.c[8]));
                offi += ex;
                f32x2 s2;
                s2.x = s2.y = __builtin_bit_cast(float, (u32)(127 - ex) << 23);
                #pragma unroll
                for (int q = 0; q < 8; q++) acc.p[q] *= s2;
            }
            if (i == 7 && defer){
                int ex = exref(fmaxf(acc.c[0], acc.c[8]));
                offi += ex;
                exf = (float)ex;
            }

            // pack C/D straight into B regs (lane-local; applies rho implicitly)
            B0v[0] = pkbf_t(acc.c[0],  acc.c[1]);  B0v[1] = pkbf_t(acc.c[2],  acc.c[3]);
            B0v[2] = pkbf_t(acc.c[4],  acc.c[5]);  B0v[3] = pkbf_t(acc.c[6],  acc.c[7]);
            B1v[0] = pkbf_t(acc.c[8],  acc.c[9]);  B1v[1] = pkbf_t(acc.c[10], acc.c[11]);
            B1v[2] = pkbf_t(acc.c[12], acc.c[13]); B1v[3] = pkbf_t(acc.c[14], acc.c[15]);
        }
    };

    issue(eA, 0); commit(eA, 0);
    #pragma unroll 1
    for (int k = 0; k < 14; k += 2){
        issue(eB, k + 1);
        procN(k, true, ic<8>{});
        commit(eB, k + 1);
        issue(eA, k + 2);
        procN(k + 1, true, ic<8>{});
        commit(eA, k + 2);
    }
    issue(eB, 15);
    procN(14, true, ic<8>{});
    commit(eB, 15);
    if (c != 7) procN(15, false, ic<8>{});   // wave-uniform branch
    else        procN(15, false, ic<7>{});   // chunk 7 has 127 steps

    // ---- store frag contiguously per lane: wmat[bc*512 + lt*8 + d] (2x dwordx4)
    {
        u32* wp = wmat + (size_t)bc * 512 + (size_t)lt * 8;
        *(u32x4*)(wp)     = B0v;
        *(u32x4*)(wp + 4) = B1v;
    }
    if (lt == 0) woff[bc] = (float)offi;

    // ---- gold for this chunk's 128 positions (t = tbeg..tbeg+127), 2/lane.
    // Post-loop (r4/r5-verified): emissions just streamed by this wave -> cache-hot.
    {
        const int t1 = tbeg + 2*lt;
        const int t2 = t1 + 1;
        const int i2 = t2 > (NS-1) ? (NS-1) : t2;   // c==7,lt==63: t2==1024
        const int g0 = tags[tb + t1 - 1];
        const int g1 = tags[tb + t1];
        const int g2 = tags[tb + i2];
        float gg = 0.0f;
        if (t1 < len) gg += base[t1*NT + g1] + trans[g0*NT + g1];
        if (t2 < len) gg += base[t2*NT + g2] + trans[g1*NT + g2];
        #pragma unroll
        for (int d = 1; d < 64; d <<= 1) gg += __shfl_xor(gg, d, 64);
        if (lt == 0){
            if (c == 0) gg += base[tags[tb]];        // t=0 emission
            gpart[bc] = gg;                          // plain store, no atomic
        }
    }
}

// ---------------- Phase 2: per-batch MFMA matrix-chain combine ----------------
// 256 blocks x 4 waves; wave = one batch, fully independent (no LDS/sync).
// Identity: mfma(frag(X), frag(Y)) = X^T * Y in true space, because the stored
// A/B fragment packings are element-identical and rho is a bijection over k.
// Chain S <- pack(M_j^T * S), j=7..0, base S=frag(I)  =>  S = (M7*...*M0)^T = C^T.
// Final: mfma(frag(S), frag(v0*1^T)) = C*v0 broadcast over cols; row-sum gives
// 1^T C v0. Each matrix loaded exactly once (2 uint4/lane); all 16 loads issued
// up front so the serial MFMA chain sits under one load latency.
__global__ __launch_bounds__(256) void crf_combine(
    const float* __restrict__ logits,
    const u32* __restrict__ wmat, const float* __restrict__ woff,
    const float* __restrict__ gpart, float* __restrict__ out)
{
    const int tid = threadIdx.x;
    const int wv  = tid >> 6, lt = tid & 63;
    const int m   = lt & 31,  h  = lt >> 5;
    const int b   = blockIdx.x * 4 + wv;
    const float* base = logits + (size_t)b * NS * NT;

    // issue all 8 matrix fragment loads first (independent, 16 dwordx4 in flight)
    uint4 mf[16];
    const u32* wb = wmat + (size_t)b * 8 * 512 + (size_t)lt * 8;
    #pragma unroll
    for (int j = 0; j < 8; j++){
        mf[2*j]     = *(const uint4*)(wb + j*512);
        mf[2*j + 1] = *(const uint4*)(wb + j*512 + 4);
    }

    // gold: fold 8 chunk partials (t=0 emission already inside gpart[b*8+0])
    float4 gp0 = ((const float4*)(gpart + b*8))[0];
    float4 gp1 = ((const float4*)(gpart + b*8))[1];
    const float gold = (gp0.x + gp0.y) + (gp0.z + gp0.w)
                     + (gp1.x + gp1.y) + (gp1.z + gp1.w);

    float voff = 0.0f;
    #pragma unroll
    for (int cc = 0; cc < 8; cc++) voff += woff[b*8 + cc];

    // S = stored(I): slot k holds row rho(k) of I
    u32x4 S0, S1;
    #pragma unroll
    for (int d = 0; d < 4; d++){
        int k0 = 8*h + 2*d;      u32 v = 0;
        if (rho(k0)     == m) v |= 0x3F80u;
        if (rho(k0 + 1) == m) v |= 0x3F800000u;
        S0[d] = v;
        int k1 = 16 + 8*h + 2*d; v = 0;
        if (rho(k1)     == m) v |= 0x3F80u;
        if (rho(k1 + 1) == m) v |= 0x3F800000u;
        S1[d] = v;
    }

    cfrag zacc;
    #pragma unroll
    for (int q = 0; q < 16; q++) zacc[q] = 0.0f;

    // chain j = 7..0: S <- pack(renorm(M_j^T * S))
    #pragma unroll
    for (int j = 7; j >= 0; j--){
        accu acc;
        acc.c = __builtin_amdgcn_mfma_f32_32x32x16_bf16(
                    __builtin_bit_cast(bfrag, mf[2*j]),
                    __builtin_bit_cast(bfrag, S0), zacc, 0, 0, 0);
        acc.c = __builtin_amdgcn_mfma_f32_32x32x16_bf16(
                    __builtin_bit_cast(bfrag, mf[2*j + 1]),
                    __builtin_bit_cast(bfrag, S1), acc.c, 0, 0, 0);

        // full-max power-of-2 renorm (wave-uniform)
        float mx = acc.c[0];
        #pragma unroll
        for (int q = 1; q < 16; q++) mx = fmaxf(mx, acc.c[q]);
        #pragma unroll
        for (int d = 1; d < 64; d <<= 1) mx = fmaxf(mx, __shfl_xor(mx, d, 64));
        int ex = exref(mx);
        float sc = __builtin_bit_cast(float, (u32)(127 - ex) << 23);
        #pragma unroll
        for (int q = 0; q < 16; q++) acc.c[q] *= sc;
        voff += (float)ex;

        S0[0] = pkbf_t(acc.c[0],  acc.c[1]);  S0[1] = pkbf_t(acc.c[2],  acc.c[3]);
        S0[2] = pkbf_t(acc.c[4],  acc.c[5]);  S0[3] = pkbf_t(acc.c[6],  acc.c[7]);
        S1[0] = pkbf_t(acc.c[8],  acc.c[9]);  S1[1] = pkbf_t(acc.c[10], acc.c[11]);
        S1[2] = pkbf_t(acc.c[12], acc.c[13]); S1[3] = pkbf_t(acc.c[14], acc.c[15]);
    }

    // V = stored(v0 * 1^T): slot k (all lanes) = v0[rho(k)] = exp2(L2E*emit0[rho(k)])
    u32x4 V0, V1;
    #pragma unroll
    for (int d = 0; d < 4; d++){
        int k0 = 8*h + 2*d;
        V0[d] = pkbf_rne(fexp2(L2E * base[rho(k0)]), fexp2(L2E * base[rho(k0+1)]));
        int k1 = 16 + 8*h + 2*d;
        V1[d] = pkbf_rne(fexp2(L2E * base[rho(k1)]), fexp2(L2E * base[rho(k1+1)]));
    }

    accu fin;
    fin.c = __builtin_amdgcn_mfma_f32_32x32x16_bf16(
                __builtin_bit_cast(bfrag, S0), __builtin_bit_cast(bfrag, V0),
                zacc, 0, 0, 0);
    fin.c = __builtin_amdgcn_mfma_f32_32x32x16_bf16(
                __builtin_bit_cast(bfrag, S1), __builtin_bit_cast(bfrag, V1),
                fin.c, 0, 0, 0);

    // D[m][n] = (C v0)[m] for every n; lane sums its 16 rows, h-swap completes.
    float s = 0.0f;
    #pragma unroll
    for (int q = 0; q < 16; q++) s += fin.c[q];
    s += __shfl_xor(s, 32, 64);

    if (lt == 0){
        float logz = LN2 * (voff + flog2(s));
        atomicAdd(out, (logz - gold) * (1.0f / (float)NB));
    }
}

extern "C" void kernel_launch(void* const* d_in, const int* in_sizes, int n_in,
                              void* d_out, int out_size, void* d_ws, size_t ws_size,
                              hipStream_t stream) {
    const float* logits = (const float*)d_in[0];
    const float* trans  = (const float*)d_in[1];
    const int*   tags   = (const int*)d_in[2];
    const int*   lens   = (const int*)d_in[3];

    u32*   wmat  = (u32*)d_ws;                                   // 16 MB
    float* woff  = (float*)((char*)d_ws + 16u*1024u*1024u);      // 32 KB
    float* gpart = woff + 8192;                                  // 32 KB

    crf_chunk  <<<2048, 256, 0, stream>>>(logits, trans, tags, lens,
                                          wmat, woff, gpart, (float*)d_out);
    crf_combine<<< 256, 256, 0, stream>>>(logits, wmat, woff, gpart,
                                          (float*)d_out);
}

// Round 7
// 248.343 us; speedup vs baseline: 3.8043x; 1.0005x over previous
//
#include <hip/hip_runtime.h>

#define NB 1024
#define NS 1024
#define NT 32
#define L2E 1.44269504088896340736f
#define LN2 0.69314718055994530942f

typedef short        bfrag  __attribute__((ext_vector_type(8)));   // 8 bf16 (4 VGPR)
typedef float        cfrag  __attribute__((ext_vector_type(16)));  // 16 f32 acc
typedef __bf16       bf16x2 __attribute__((ext_vector_type(2)));
typedef float        f32x8  __attribute__((ext_vector_type(8)));
typedef float        f32x4  __attribute__((ext_vector_type(4)));
typedef float        f32x2  __attribute__((ext_vector_type(2)));
typedef unsigned int u32;
typedef unsigned int u32x4  __attribute__((ext_vector_type(4)));

__device__ __forceinline__ float fexp2(float x){ return __builtin_amdgcn_exp2f(x); }
__device__ __forceinline__ float flog2(float x){ return __builtin_amdgcn_logf(x); }

// RNE pack (prologue only)
__device__ __forceinline__ u32 pkbf_rne(float a, float b){
    f32x2 t; t.x = a; t.y = b;
    return __builtin_bit_cast(u32, __builtin_convertvector(t, bf16x2));
}
// truncation pack: single v_perm_b32. low16 = bf16_trunc(a), high16 = bf16_trunc(b).
__device__ __forceinline__ u32 pkbf_t(float a, float b){
    return __builtin_amdgcn_perm(__builtin_bit_cast(u32, b),
                                 __builtin_bit_cast(u32, a), 0x07060302u);
}
__device__ __forceinline__ bfrag mk_afrag(f32x8 v){
    u32x4 r;
    r[0] = pkbf_rne(v[0], v[1]); r[1] = pkbf_rne(v[2], v[3]);
    r[2] = pkbf_rne(v[4], v[5]); r[3] = pkbf_rne(v[6], v[7]);
    return __builtin_bit_cast(bfrag, r);
}
// wave-uniform power-of-2 exponent extract (clamped)
__device__ __forceinline__ int exref(float ref){
    u32 xb = __builtin_bit_cast(u32, ref);
    u32 xf = __builtin_amdgcn_readfirstlane(xb);
    int ex = (int)((xf >> 23) & 0xFFu) - 127;
    return ex < -120 ? -120 : (ex > 120 ? 120 : ex);
}

// row-space involution applied implicitly by packing C/D straight into B regs:
// swaps row blocks [4..7]<->[8..11] and [20..23]<->[24..27].
__device__ __forceinline__ int rho(int k){
    int bb = (k >> 2) & 3;
    return (bb == 1 || bb == 2) ? (k ^ 12) : k;
}

template<int N> struct ic { static constexpr int value = N; };
union accu { cfrag c; f32x2 p[8]; };
union q4u  { f32x4 v; f32x2 p[2]; };

#define MFMA(A,B,C) __builtin_amdgcn_mfma_f32_32x32x16_bf16( \
    (A), __builtin_bit_cast(bfrag, B), (C), 0, 0, 0)

// ---------------- Phase 1: per-(batch,chunk) transfer matrix + gold ----------
// Dual-ILP version: each wave advances TWO independent 64-step half-chains
// (lo/hi) interleaved at step granularity — chain H's ops fill chain L's
// MFMA->scale->pack dependency gaps (the r6 kernel was stall-bound: no pipe
// above ~55%). Wave-end merge via the r6-verified transpose identity:
//   G = pack(mfma2(frag(M_hi), frag(I))) = frag(M_hi^T)      (exact)
//   F = pack(renorm(mfma2(G, frag(M_lo)))) = frag(M_hi*M_lo)
// Store layout / woff / gold / combine identical to round 6.
__global__ __launch_bounds__(256, 4) void crf_chunk(
    const float* __restrict__ logits, const float* __restrict__ trans,
    const int* __restrict__ tags, const int* __restrict__ lens,
    u32* __restrict__ wmat, float* __restrict__ woff,
    float* __restrict__ gpart, float* __restrict__ outz)
{
    __shared__ __align__(16) float dscall[4 * 1024];  // per-wave: 2 chains x 512

    const int tid = threadIdx.x;
    const int wv  = tid >> 6, lt = tid & 63;
    const int m   = lt & 31,  h  = lt >> 5;
    const int bc  = blockIdx.x * 4 + wv;
    const int b   = bc >> 3,  c  = bc & 7;
    float* dscL = dscall + wv * 1024;
    float* dscH = dscL + 512;

    if (blockIdx.x == 0 && tid == 0) *outz = 0.0f;    // replaces memset dispatch

    const float* base = logits + (size_t)b * NS * NT;
    const int    len  = lens[b];
    const int    tb   = b * NS;

    // A frags with rho-compensated k index: A'[m][k] = exp(trans[rho(k)][m])
    f32x8 Et0, Et1;
    #pragma unroll
    for (int j = 0; j < 8; j++){
        Et0[j] = fexp2(L2E * trans[rho(     8*h + j)*NT + m]);
        Et1[j] = fexp2(L2E * trans[rho(16 + 8*h + j)*NT + m]);
    }
    const bfrag A0f = mk_afrag(Et0);
    const bfrag A1f = mk_afrag(Et1);

    // rho-permuted identity frag values (slot k holds row rho(k))
    u32x4 I0, I1;
    #pragma unroll
    for (int d = 0; d < 4; d++){
        int k0 = 8*h + 2*d;      u32 v = 0;
        if (rho(k0)     == m) v |= 0x3F80u;
        if (rho(k0 + 1) == m) v |= 0x3F800000u;
        I0[d] = v;
        int k1 = 16 + 8*h + 2*d; v = 0;
        if (rho(k1)     == m) v |= 0x3F80u;
        if (rho(k1 + 1) == m) v |= 0x3F800000u;
        I1[d] = v;
    }

    u32x4 L0 = I0, L1 = I1;      // chain lo state
    u32x4 H0 = I0, H1 = I1;      // chain hi state

    cfrag zacc;
    #pragma unroll
    for (int q = 0; q < 16; q++) zacc[q] = 0.0f;

    int   offiL = 0,    offiH = 0;     // per-chain accumulated log2 scales
    float exfL  = 0.0f, exfH  = 0.0f;  // per-chain deferred scales
    const int tbegL = c*128 + 1;       // lo: 64 steps
    const int tbegH = c*128 + 65;      // hi: 64 steps (63 for c==7)

    float eLA[4], eLB[4], eHA[4], eHB[4];

    auto issue = [&](float (&e)[4], int k, int tbeg){
        const int t0 = tbeg + k*8 + 4*h;
        #pragma unroll
        for (int i = 0; i < 4; i++){
            int t = t0 + i; t = t > (NS-1) ? (NS-1) : t;   // clamp c==7 tail
            e[i] = base[t*NT + m];
        }
    };
    auto commit = [&](float (&e)[4], int k, float* dsc, float exf){
        float* sp = dsc + (k & 1)*256 + (4*h)*32 + m;
        float a0 = (h == 0) ? -exf : 0.0f;
        sp[0]    = fexp2(fmaf(L2E, e[0], a0));
        sp[32]   = fexp2(L2E * e[1]);
        sp[64]   = fexp2(L2E * e[2]);
        sp[96]   = fexp2(L2E * e[3]);
    };

    // one k-group (8 steps) of BOTH chains, step-interleaved. NH<8 only on the
    // very last group of c==7 (defer==false there).
    auto proc2 = [&](int k, bool defer, auto nhC){
        constexpr int NH = decltype(nhC)::value;
        const float* dbL = dscL + (k & 1)*256 + 4*h;
        const float* dbH = dscH + (k & 1)*256 + 4*h;
        #pragma unroll
        for (int i = 0; i < 8; i++){
            accu aL, aH;
            aL.c = MFMA(A0f, L0, zacc);
            if (i < NH) aH.c = MFMA(A0f, H0, zacc);
            aL.c = MFMA(A1f, L1, aL.c);
            if (i < NH) aH.c = MFMA(A1f, H1, aH.c);

            {   // D_t row scales, chain L
                q4u d0, d1, d2, d3;
                d0.v = *(const f32x4*)(dbL + i*32 +  0);
                d1.v = *(const f32x4*)(dbL + i*32 +  8);
                d2.v = *(const f32x4*)(dbL + i*32 + 16);
                d3.v = *(const f32x4*)(dbL + i*32 + 24);
                aL.p[0] *= d0.p[0]; aL.p[1] *= d0.p[1];
                aL.p[2] *= d1.p[0]; aL.p[3] *= d1.p[1];
                aL.p[4] *= d2.p[0]; aL.p[5] *= d2.p[1];
                aL.p[6] *= d3.p[0]; aL.p[7] *= d3.p[1];
            }
            if (i < NH){ // D_t row scales, chain H
                q4u d0, d1, d2, d3;
                d0.v = *(const f32x4*)(dbH + i*32 +  0);
                d1.v = *(const f32x4*)(dbH + i*32 +  8);
                d2.v = *(const f32x4*)(dbH + i*32 + 16);
                d3.v = *(const f32x4*)(dbH + i*32 + 24);
                aH.p[0] *= d0.p[0]; aH.p[1] *= d0.p[1];
                aH.p[2] *= d1.p[0]; aH.p[3] *= d1.p[1];
                aH.p[4] *= d2.p[0]; aH.p[5] *= d2.p[1];
                aH.p[6] *= d3.p[0]; aH.p[7] *= d3.p[1];
            }

            if (i == 3){
                int exL = exref(fmaxf(aL.c[0], aL.c[8]));
                offiL += exL;
                f32x2 s2; s2.x = s2.y =
                    __builtin_bit_cast(float, (u32)(127 - exL) << 23);
                #pragma unroll
                for (int q = 0; q < 8; q++) aL.p[q] *= s2;
                int exH = exref(fmaxf(aH.c[0], aH.c[8]));
                offiH += exH;
                f32x2 s3; s3.x = s3.y =
                    __builtin_bit_cast(float, (u32)(127 - exH) << 23);
                #pragma unroll
                for (int q = 0; q < 8; q++) aH.p[q] *= s3;
            }
            if (i == 7 && defer){
                int exL = exref(fmaxf(aL.c[0], aL.c[8]));
                offiL += exL; exfL = (float)exL;
                int exH = exref(fmaxf(aH.c[0], aH.c[8]));
                offiH += exH; exfH = (float)exH;
            }

            L0[0] = pkbf_t(aL.c[0],  aL.c[1]);  L0[1] = pkbf_t(aL.c[2],  aL.c[3]);
            L0[2] = pkbf_t(aL.c[4],  aL.c[5]);  L0[3] = pkbf_t(aL.c[6],  aL.c[7]);
            L1[0] = pkbf_t(aL.c[8],  aL.c[9]);  L1[1] = pkbf_t(aL.c[10], aL.c[11]);
            L1[2] = pkbf_t(aL.c[12], aL.c[13]); L1[3] = pkbf_t(aL.c[14], aL.c[15]);
            if (i < NH){
                H0[0] = pkbf_t(aH.c[0],  aH.c[1]);  H0[1] = pkbf_t(aH.c[2],  aH.c[3]);
                H0[2] = pkbf_t(aH.c[4],  aH.c[5]);  H0[3] = pkbf_t(aH.c[6],  aH.c[7]);
                H1[0] = pkbf_t(aH.c[8],  aH.c[9]);  H1[1] = pkbf_t(aH.c[10], aH.c[11]);
                H1[2] = pkbf_t(aH.c[12], aH.c[13]); H1[3] = pkbf_t(aH.c[14], aH.c[15]);
            }
        }
    };

    issue(eLA, 0, tbegL); issue(eHA, 0, tbegH);
    commit(eLA, 0, dscL, 0.0f); commit(eHA, 0, dscH, 0.0f);
    #pragma unroll 1
    for (int k = 0; k < 6; k += 2){
        issue(eLB, k + 1, tbegL); issue(eHB, k + 1, tbegH);
        proc2(k, true, ic<8>{});
        commit(eLB, k + 1, dscL, exfL); commit(eHB, k + 1, dscH, exfH);
        issue(eLA, k + 2, tbegL); issue(eHA, k + 2, tbegH);
        proc2(k + 1, true, ic<8>{});
        commit(eLA, k + 2, dscL, exfL); commit(eHA, k + 2, dscH, exfH);
    }
    issue(eLB, 7, tbegL); issue(eHB, 7, tbegH);
    proc2(6, true, ic<8>{});
    commit(eLB, 7, dscL, exfL); commit(eHB, 7, dscH, exfH);
    if (c != 7) proc2(7, false, ic<8>{});   // wave-uniform branch
    else        proc2(7, false, ic<7>{});   // hi chain of chunk 7 has 63 steps

    // ---- merge: F = M_hi * M_lo in stored convention
    u32x4 F0, F1;
    int offi;
    {
        accu tt;                      // T = M_hi^T (exact: product with identity)
        tt.c = MFMA(__builtin_bit_cast(bfrag, H0), I0, zacc);
        tt.c = MFMA(__builtin_bit_cast(bfrag, H1), I1, tt.c);
        u32x4 G0, G1;
        G0[0] = pkbf_t(tt.c[0],  tt.c[1]);  G0[1] = pkbf_t(tt.c[2],  tt.c[3]);
        G0[2] = pkbf_t(tt.c[4],  tt.c[5]);  G0[3] = pkbf_t(tt.c[6],  tt.c[7]);
        G1[0] = pkbf_t(tt.c[8],  tt.c[9]);  G1[1] = pkbf_t(tt.c[10], tt.c[11]);
        G1[2] = pkbf_t(tt.c[12], tt.c[13]); G1[3] = pkbf_t(tt.c[14], tt.c[15]);

        accu zz;                      // Z = (M_hi^T)^T * M_lo = M_hi * M_lo
        zz.c = MFMA(__builtin_bit_cast(bfrag, G0), L0, zacc);
        zz.c = MFMA(__builtin_bit_cast(bfrag, G1), L1, zz.c);

        float mx = zz.c[0];
        #pragma unroll
        for (int q = 1; q < 16; q++) mx = fmaxf(mx, zz.c[q]);
        #pragma unroll
        for (int d = 1; d < 64; d <<= 1) mx = fmaxf(mx, __shfl_xor(mx, d, 64));
        int ex = exref(mx);
        float sc = __builtin_bit_cast(float, (u32)(127 - ex) << 23);
        #pragma unroll
        for (int q = 0; q < 16; q++) zz.c[q] *= sc;
        offi = offiL + offiH + ex;

        F0[0] = pkbf_t(zz.c[0],  zz.c[1]);  F0[1] = pkbf_t(zz.c[2],  zz.c[3]);
        F0[2] = pkbf_t(zz.c[4],  zz.c[5]);  F0[3] = pkbf_t(zz.c[6],  zz.c[7]);
        F1[0] = pkbf_t(zz.c[8],  zz.c[9]);  F1[1] = pkbf_t(zz.c[10], zz.c[11]);
        F1[2] = pkbf_t(zz.c[12], zz.c[13]); F1[3] = pkbf_t(zz.c[14], zz.c[15]);
    }

    // ---- store frag contiguously per lane: wmat[bc*512 + lt*8 + d] (2x dwordx4)
    {
        u32* wp = wmat + (size_t)bc * 512 + (size_t)lt * 8;
        *(u32x4*)(wp)     = F0;
        *(u32x4*)(wp + 4) = F1;
    }
    if (lt == 0) woff[bc] = (float)offi;

    // ---- gold for this chunk's 128 positions (t = tbegL..tbegL+127), 2/lane.
    {
        const int t1 = tbegL + 2*lt;
        const int t2 = t1 + 1;
        const int i2 = t2 > (NS-1) ? (NS-1) : t2;   // c==7,lt==63: t2==1024
        const int g0 = tags[tb + t1 - 1];
        const int g1 = tags[tb + t1];
        const int g2 = tags[tb + i2];
        float gg = 0.0f;
        if (t1 < len) gg += base[t1*NT + g1] + trans[g0*NT + g1];
        if (t2 < len) gg += base[t2*NT + g2] + trans[g1*NT + g2];
        #pragma unroll
        for (int d = 1; d < 64; d <<= 1) gg += __shfl_xor(gg, d, 64);
        if (lt == 0){
            if (c == 0) gg += base[tags[tb]];        // t=0 emission
            gpart[bc] = gg;                          // plain store, no atomic
        }
    }
}

// ---------------- Phase 2: per-batch MFMA matrix-chain combine ----------------
// UNCHANGED from round 6 (verified).
__global__ __launch_bounds__(256) void crf_combine(
    const float* __restrict__ logits,
    const u32* __restrict__ wmat, const float* __restrict__ woff,
    const float* __restrict__ gpart, float* __restrict__ out)
{
    const int tid = threadIdx.x;
    const int wv  = tid >> 6, lt = tid & 63;
    const int m   = lt & 31,  h  = lt >> 5;
    const int b   = blockIdx.x * 4 + wv;
    const float* base = logits + (size_t)b * NS * NT;

    uint4 mf[16];
    const u32* wb = wmat + (size_t)b * 8 * 512 + (size_t)lt * 8;
    #pragma unroll
    for (int j = 0; j < 8; j++){
        mf[2*j]     = *(const uint4*)(wb + j*512);
        mf[2*j + 1] = *(const uint4*)(wb + j*512 + 4);
    }

    float4 gp0 = ((const float4*)(gpart + b*8))[0];
    float4 gp1 = ((const float4*)(gpart + b*8))[1];
    const float gold = (gp0.x + gp0.y) + (gp0.z + gp0.w)
                     + (gp1.x + gp1.y) + (gp1.z + gp1.w);

    float voff = 0.0f;
    #pragma unroll
    for (int cc = 0; cc < 8; cc++) voff += woff[b*8 + cc];

    u32x4 S0, S1;
    #pragma unroll
    for (int d = 0; d < 4; d++){
        int k0 = 8*h + 2*d;      u32 v = 0;
        if (rho(k0)     == m) v |= 0x3F80u;
        if (rho(k0 + 1) == m) v |= 0x3F800000u;
        S0[d] = v;
        int k1 = 16 + 8*h + 2*d; v = 0;
        if (rho(k1)     == m) v |= 0x3F80u;
        if (rho(k1 + 1) == m) v |= 0x3F800000u;
        S1[d] = v;
    }

    cfrag zacc;
    #pragma unroll
    for (int q = 0; q < 16; q++) zacc[q] = 0.0f;

    #pragma unroll
    for (int j = 7; j >= 0; j--){
        accu acc;
        acc.c = MFMA(__builtin_bit_cast(bfrag, mf[2*j]),     S0, zacc);
        acc.c = MFMA(__builtin_bit_cast(bfrag, mf[2*j + 1]), S1, acc.c);

        float mx = acc.c[0];
        #pragma unroll
        for (int q = 1; q < 16; q++) mx = fmaxf(mx, acc.c[q]);
        #pragma unroll
        for (int d = 1; d < 64; d <<= 1) mx = fmaxf(mx, __shfl_xor(mx, d, 64));
        int ex = exref(mx);
        float sc = __builtin_bit_cast(float, (u32)(127 - ex) << 23);
        #pragma unroll
        for (int q = 0; q < 16; q++) acc.c[q] *= sc;
        voff += (float)ex;

        S0[0] = pkbf_t(acc.c[0],  acc.c[1]);  S0[1] = pkbf_t(acc.c[2],  acc.c[3]);
        S0[2] = pkbf_t(acc.c[4],  acc.c[5]);  S0[3] = pkbf_t(acc.c[6],  acc.c[7]);
        S1[0] = pkbf_t(acc.c[8],  acc.c[9]);  S1[1] = pkbf_t(acc.c[10], acc.c[11]);
        S1[2] = pkbf_t(acc.c[12], acc.c[13]); S1[3] = pkbf_t(acc.c[14], acc.c[15]);
    }

    u32x4 V0, V1;
    #pragma unroll
    for (int d = 0; d < 4; d++){
        int k0 = 8*h + 2*d;
        V0[d] = pkbf_rne(fexp2(L2E * base[rho(k0)]), fexp2(L2E * base[rho(k0+1)]));
        int k1 = 16 + 8*h + 2*d;
        V1[d] = pkbf_rne(fexp2(L2E * base[rho(k1)]), fexp2(L2E * base[rho(k1+1)]));
    }

    accu fin;
    fin.c = MFMA(__builtin_bit_cast(bfrag, S0), V0, zacc);
    fin.c = MFMA(__builtin_bit_cast(bfrag, S1), V1, fin.c);

    float s = 0.0f;
    #pragma unroll
    for (int q = 0; q < 16; q++) s += fin.c[q];
    s += __shfl_xor(s, 32, 64);

    if (lt == 0){
        float logz = LN2 * (voff + flog2(s));
        atomicAdd(out, (logz - gold) * (1.0f / (float)NB));
    }
}

extern "C" void kernel_launch(void* const* d_in, const int* in_sizes, int n_in,
                              void* d_out, int out_size, void* d_ws, size_t ws_size,
                              hipStream_t stream) {
    const float* logits = (const float*)d_in[0];
    const float* trans  = (const float*)d_in[1];
    const int*   tags   = (const int*)d_in[2];
    const int*   lens   = (const int*)d_in[3];

    u32*   wmat  = (u32*)d_ws;                                   // 16 MB
    float* woff  = (float*)((char*)d_ws + 16u*1024u*1024u);      // 32 KB
    float* gpart = woff + 8192;                                  // 32 KB

    crf_chunk  <<<2048, 256, 0, stream>>>(logits, trans, tags, lens,
                                          wmat, woff, gpart, (float*)d_out);
    crf_combine<<< 256, 256, 0, stream>>>(logits, wmat, woff, gpart,
                                          (float*)d_out);
}